// Round 2
// baseline (84.019 us; speedup 1.0000x reference)
//
#include <hip/hip_runtime.h>

// IDW, POWER=2.0 -> w = 1/d2 (sqrt cancels). out = sum(w*v)/sum(w).
// B=2, P=131072, S=512.
// R7 (resubmit; last round failed on container acquisition, kernel never ran):
//     station data is WAVE-UNIFORM -> move it off the LDS datapath onto the
//     scalar pipe. Previously: broadcast ds_read_b128 still pays the full
//     64-lane x 16B LDS return-bus cost (~12cyc/instr, 288 cyc/chunk/CU >
//     256 cyc VALU/chunk/SIMD -> LDS bus was the binding resource, ~15.4us,
//     and overlapped poorly with VALU (kernel ~39us)).
//     Now: load stations via wave-uniform addresses from global memory ->
//     compiler emits s_load_dwordx4/x8 into SGPRs (6KB/batch, K$-resident).
//     VALU ops take station operands as SGPR sources (<=1 SGPR per instr:
//     each sub/fma reads at most one station scalar). Zero LDS traffic, no
//     staging loop, no __syncthreads. Kernel becomes pure VALU-bound:
//     floor ~13.2us (1.04e9 lane-ops / 1024 SIMDs / 0.5 inst/cyc @2.4GHz).
// dx = sx - gx (sign-flipped, squared anyway -> bit-identical numerics;
//     VOP2-friendly: SGPR goes in src0).
// 4-way rcp combine kept: 1/a+1/b+1/c+1/d = (sAB*pCD + sCD*pAB)*rcp(pAB*pCD),
//     31 plain VALU + 1 trans per 4 stations/point.
// EPS2 folded into the d2 fma chain (exact at d2==0: w -> 1/EPS^2 like ref).

#define BLOCK 256
#define S_MAX 512
#define GPT 2

__global__ __launch_bounds__(BLOCK) void idw_kernel(
    const float* __restrict__ station_coords,  // (B, S, 2)
    const float* __restrict__ station_values,  // (B, S)
    const float* __restrict__ grid_points,     // (B, P, 2)
    float* __restrict__ out,                   // (B, P)
    int P, int S) {

    const int b = blockIdx.y;

    // Wave-uniform station pointers (depend only on blockIdx.y / loop idx).
    const float4* __restrict__ sc4 =
        (const float4*)station_coords + (size_t)b * (S_MAX / 2);  // {x,y,x,y}
    const float4* __restrict__ sv4 =
        (const float4*)station_values + (size_t)b * (S_MAX / 4);  // {v,v,v,v}

    const int tid = blockIdx.x * BLOCK + threadIdx.x;
    const float4 g01 = ((const float4*)grid_points)[(size_t)b * (P / 2) + tid];
    const float gx0 = g01.x, gy0 = g01.y, gx1 = g01.z, gy1 = g01.w;

    constexpr float EPS  = 1.1920928955078125e-07f;
    constexpr float EPS2 = EPS * EPS;

    float wsum0 = 0.0f, vsum0 = 0.0f;
    float wsum1 = 0.0f, vsum1 = 0.0f;

    // 4 stations A,B,C,D vs one point: 31 plain VALU + 1 rcp.
    // c0 = {Ax,Ay,Bx,By}, c1 = {Cx,Cy,Dx,Dy}, vv = {vA,vB,vC,vD} (all SGPR).
    auto quad = [&](float gx, float gy, float& ws, float& vs,
                    const float4& c0, const float4& c1, const float4& vv) {
        const float dxa = c0.x - gx, dya = c0.y - gy;
        const float a = fmaf(dxa, dxa, fmaf(dya, dya, EPS2));
        const float dxb = c0.z - gx, dyb = c0.w - gy;
        const float bq = fmaf(dxb, dxb, fmaf(dyb, dyb, EPS2));
        const float dxc = c1.x - gx, dyc = c1.y - gy;
        const float c = fmaf(dxc, dxc, fmaf(dyc, dyc, EPS2));
        const float dxd = c1.z - gx, dyd = c1.w - gy;
        const float d = fmaf(dxd, dxd, fmaf(dyd, dyd, EPS2));
        const float pab = a * bq, pcd = c * d;
        const float sab = a + bq, scd = c + d;
        const float nab = fmaf(vv.y, a, vv.x * bq);  // vB*a + vA*b
        const float ncd = fmaf(vv.w, c, vv.z * d);   // vD*c + vC*d
        const float r = __builtin_amdgcn_rcpf(pab * pcd);
        ws = fmaf(fmaf(sab, pcd, scd * pab), r, ws);
        vs = fmaf(fmaf(nab, pcd, ncd * pab), r, vs);
    };

    // Software pipeline: prefetch chunk k+1 (scalar loads) while computing k.
    float4 c0 = sc4[0], c1 = sc4[1], vv = sv4[0];
#pragma unroll 4
    for (int k = 0; k < S_MAX / 4 - 1; ++k) {
        const float4 n0 = sc4[2 * k + 2];
        const float4 n1 = sc4[2 * k + 3];
        const float4 nv = sv4[k + 1];
        quad(gx0, gy0, wsum0, vsum0, c0, c1, vv);
        quad(gx1, gy1, wsum1, vsum1, c0, c1, vv);
        c0 = n0; c1 = n1; vv = nv;
    }
    quad(gx0, gy0, wsum0, vsum0, c0, c1, vv);
    quad(gx1, gy1, wsum1, vsum1, c0, c1, vv);

    const float r0 = vsum0 / wsum0;
    const float r1 = vsum1 / wsum1;
    ((float2*)out)[(size_t)b * (P / 2) + tid] = make_float2(r0, r1);
}

extern "C" void kernel_launch(void* const* d_in, const int* in_sizes, int n_in,
                              void* d_out, int out_size, void* d_ws, size_t ws_size,
                              hipStream_t stream) {
    const float* station_coords = (const float*)d_in[0];
    const float* station_values = (const float*)d_in[1];
    const float* grid_points    = (const float*)d_in[2];
    float* out = (float*)d_out;

    const int B = 2;
    const int S = in_sizes[1] / B;   // 512
    const int P = out_size / B;      // 131072

    dim3 grid(P / (BLOCK * GPT), B);  // 256 x 2 = 512 blocks, 2 per CU
    dim3 block(BLOCK);
    idw_kernel<<<grid, block, 0, stream>>>(station_coords, station_values,
                                           grid_points, out, P, S);
}

// Round 3
// 81.515 us; speedup vs baseline: 1.0307x; 1.0307x over previous
//
#include <hip/hip_runtime.h>

// IDW, POWER=2.0 -> w = 1/d2 (sqrt cancels). out = sum(w*v)/sum(w).
// B=2, P=131072, S=512.
// R8: post-mortem of R7 (SMEM move, neutral): LDS-vs-SMEM was never the
//     binding constraint -- both versions stall the same way. Common factor:
//     TLP = 2 waves/SIMD (512 blocks). Per chunk a wave has ~124cyc of VALU
//     work per SIMD; 2 waves give ~248cyc to cover ~200cyc SMEM latency plus
//     fma dep-chain bubbles -> zero slack, latency-bound at ~3x VALU floor.
//     Fix: GPT=1 -> 1024 blocks -> 4 waves/SIMD (2x latency-hiding slack).
//     Station loads stay on the scalar pipe (SGPR, K$-resident 6KB/batch) so
//     doubling wave count adds ~no datapath cost (the reason R7's move still
//     pays off here; the LDS version would double LDS bus traffic).
//     Also: drop the manual distance-1 rotation pipeline -- it handcuffed the
//     scheduler. Direct indexing + #pragma unroll 8 lets the compiler merge
//     adjacent wave-uniform loads (s_load_dwordx8/x16: 8 chunks of coords are
//     256B contiguous) and hoist them a full unrolled body ahead.
// Per-point math unchanged (bit-identical): 4-way rcp combine,
//     1/a+1/b+1/c+1/d = (sAB*pCD + sCD*pAB)*rcp(pAB*pCD),
//     ~30 plain VALU + 1 trans per 4 stations/point. EPS2 folded into the d2
//     fma chain (exact at d2==0: w -> 1/EPS^2 like ref).
// dx = sx - gx (sign-flipped, squared anyway; VOP2-friendly: SGPR in src0;
//     every VALU op reads <=1 SGPR so scalar station operands are legal).

#define BLOCK 256
#define S_MAX 512

__global__ __launch_bounds__(BLOCK) void idw_kernel(
    const float* __restrict__ station_coords,  // (B, S, 2)
    const float* __restrict__ station_values,  // (B, S)
    const float* __restrict__ grid_points,     // (B, P, 2)
    float* __restrict__ out,                   // (B, P)
    int P, int S) {

    const int b = blockIdx.y;

    // Wave-uniform station pointers -> scalar loads into SGPRs.
    const float4* __restrict__ sc4 =
        (const float4*)station_coords + (size_t)b * (S_MAX / 2);  // {x,y,x,y}
    const float4* __restrict__ sv4 =
        (const float4*)station_values + (size_t)b * (S_MAX / 4);  // {v,v,v,v}

    const int tid = blockIdx.x * BLOCK + threadIdx.x;
    const float2 g = ((const float2*)grid_points)[(size_t)b * P + tid];
    const float gx = g.x, gy = g.y;

    constexpr float EPS  = 1.1920928955078125e-07f;
    constexpr float EPS2 = EPS * EPS;

    float wsum = 0.0f, vsum = 0.0f;

    // 4 stations A,B,C,D vs one point: ~30 plain VALU + 1 rcp.
    // c0 = {Ax,Ay,Bx,By}, c1 = {Cx,Cy,Dx,Dy}, vv = {vA,vB,vC,vD} (all SGPR).
#pragma unroll 8
    for (int k = 0; k < S_MAX / 4; ++k) {
        const float4 c0 = sc4[2 * k + 0];
        const float4 c1 = sc4[2 * k + 1];
        const float4 vv = sv4[k];

        const float dxa = c0.x - gx, dya = c0.y - gy;
        const float a = fmaf(dxa, dxa, fmaf(dya, dya, EPS2));
        const float dxb = c0.z - gx, dyb = c0.w - gy;
        const float bq = fmaf(dxb, dxb, fmaf(dyb, dyb, EPS2));
        const float dxc = c1.x - gx, dyc = c1.y - gy;
        const float c = fmaf(dxc, dxc, fmaf(dyc, dyc, EPS2));
        const float dxd = c1.z - gx, dyd = c1.w - gy;
        const float d = fmaf(dxd, dxd, fmaf(dyd, dyd, EPS2));
        const float pab = a * bq, pcd = c * d;
        const float sab = a + bq, scd = c + d;
        const float nab = fmaf(vv.y, a, vv.x * bq);  // vB*a + vA*b
        const float ncd = fmaf(vv.w, c, vv.z * d);   // vD*c + vC*d
        const float r = __builtin_amdgcn_rcpf(pab * pcd);
        wsum = fmaf(fmaf(sab, pcd, scd * pab), r, wsum);
        vsum = fmaf(fmaf(nab, pcd, ncd * pab), r, vsum);
    }

    out[(size_t)b * P + tid] = vsum / wsum;
}

extern "C" void kernel_launch(void* const* d_in, const int* in_sizes, int n_in,
                              void* d_out, int out_size, void* d_ws, size_t ws_size,
                              hipStream_t stream) {
    const float* station_coords = (const float*)d_in[0];
    const float* station_values = (const float*)d_in[1];
    const float* grid_points    = (const float*)d_in[2];
    float* out = (float*)d_out;

    const int B = 2;
    const int S = in_sizes[1] / B;   // 512
    const int P = out_size / B;      // 131072

    dim3 grid(P / BLOCK, B);  // 512 x 2 = 1024 blocks, 4/CU -> 4 waves/SIMD
    dim3 block(BLOCK);
    idw_kernel<<<grid, block, 0, stream>>>(station_coords, station_values,
                                           grid_points, out, P, S);
}